// Round 11
// baseline (6698.772 us; speedup 1.0000x reference)
//
#include <hip/hip_runtime.h>
#include <math.h>

#define NN 4096
#define DIM 784
#define K62 62
#define CAP 128

// ---------------- init ----------------
__global__ __launch_bounds__(64) void k_init(double* Ssum, double* Lsum) {
    if (threadIdx.x == 0) { Ssum[0] = 0.0; Lsum[0] = 0.0; }
}

// ---------------- squared row norms: f64 exact + f32 for keys ----------------
__global__ __launch_bounds__(256) void k_sqnorm(const float* __restrict__ x, double* __restrict__ sqnd,
                                                float* __restrict__ sqnf) {
    int r = blockIdx.x * 4 + (threadIdx.x >> 6);
    int lane = threadIdx.x & 63;
    const float* xr = x + (size_t)r * DIM;
    double s = 0.0;
    for (int k = lane; k < DIM; k += 64) { double v = (double)xr[k]; s += v * v; }
    for (int o = 32; o > 0; o >>= 1) s += __shfl_down(s, o);
    if (lane == 0) { sqnd[r] = s; sqnf[r] = (float)s; }
}

// ---------------- fused all-f64 encoder: 25744 B LDS -> 6 blocks/CU ----------------
// simg kept f32 (cvt-per-use in conv1 is cheap; exact), weights f64-staged (R10 win).
// Phase layout (audited, no live overlap):
//  fixed:  biases[0,384)
//  phase1: simg f32[384,3984) scw1 d[3984,6288) h1q[6288,16528) wq[16528,25744)
//  phase2: wq3[384,9600) h2s[9600,22536)
//  phase3: c3[9600,15872) red[15872,17920) se[17920,18048)
__global__ __launch_bounds__(256, 6) void k_encoder(const float* __restrict__ x,
    const float* __restrict__ cw1, const float* __restrict__ cb1,
    const float* __restrict__ cw2, const float* __restrict__ cb2,
    const float* __restrict__ cw3, const float* __restrict__ cb3,
    const float* __restrict__ dw, const float* __restrict__ db,
    double* __restrict__ Enc, double* __restrict__ esqd)
{
    __shared__ __align__(16) unsigned char SB[25744];
    float*  sb1  = (float*)(SB);             // 32 f  [0,128)
    float*  sb2  = (float*)(SB + 128);       // 32 f  [128,256)
    float*  sb3  = (float*)(SB + 256);       // 16 f  [256,320)
    float*  sdb  = (float*)(SB + 320);       // 16 f  [320,384)
    float*  simg = (float*)(SB + 384);       // 900 f = 3600  [384,3984)
    double* scw1 = (double*)(SB + 3984);     // 288 d = 2304  [3984,6288)
    double* h1q  = (double*)(SB + 6288);     // 1280 d = 10240 [6288,16528)
    double* wq   = (double*)(SB + 16528);    // 1152 d = 9216  [16528,25744)
    // overlays (phase 2/3; legality guarded by the existing syncs):
    double* wq3  = (double*)(SB + 384);      // 1152 d over simg+scw1+h1q-head (all dead in phase 2)
    double* h2s  = (double*)(SB + 9600);     // 1617 d over h1q-tail+wq (dead in phase 2)
    double* c3   = (double*)(SB + 9600);     // 784 d over h2s head (after conv3 reads)
    double* red  = (double*)(SB + 15872);    // 256 d
    double* se   = (double*)(SB + 17920);    // 16 d

    int n = blockIdx.x, t = threadIdx.x;
    // zero padded buffers
    for (int idx = t; idx < 1280; idx += 256) h1q[idx] = 0.0;
    for (int idx = t; idx < 900; idx += 256) simg[idx] = 0.f;
    __syncthreads();
    // load image interior (28 rows of 7 float4); cw1 cvt once to f64; biases f32
    if (t < 196) {
        int row = t / 7, c4 = t % 7;
        float4 v = ((const float4*)(x + (size_t)n * DIM))[t];
        float* d = &simg[(row + 1) * 30 + 1 + c4 * 4];
        d[0] = v.x; d[1] = v.y; d[2] = v.z; d[3] = v.w;
    }
    for (int idx = t; idx < 288; idx += 256) scw1[idx] = (double)cw1[idx];
    if (t < 32) { sb1[t] = cb1[t]; sb2[t] = cb2[t]; }
    if (t < 16) { sb3[t] = cb3[t]; sdb[t] = db[t]; }
    __syncthreads();

    int p2 = t >> 2, co8 = (t & 3) * 8;
    int py2 = p2 / 7, px2 = p2 % 7;
    int cbase = ((2 * py2) * 16 + 2 * px2) * 5;   // padded h1q base (doubles)
    double acc[2][2][8];
    if (t < 196) {
        #pragma unroll
        for (int dy = 0; dy < 2; ++dy)
        #pragma unroll
        for (int dx = 0; dx < 2; ++dx)
        #pragma unroll
        for (int q = 0; q < 8; ++q) acc[dy][dx][q] = (double)sb2[co8 + q];
    }

    for (int oct = 0; oct < 8; ++oct) {
        __syncthreads();   // protect h1q/wq from previous octant's readers
        // ---- conv1 + relu + pool for channels [4*oct, 4*oct+4): f64 weights, f32 image (exact cvt) ----
        for (int o = t; o < 784; o += 256) {
            int ch = o & 3, p = o >> 2;
            int py = p / 14, px = p % 14;
            int co = (oct << 2) + ch;
            double wv[9];
            #pragma unroll
            for (int tp = 0; tp < 9; ++tp) wv[tp] = scw1[tp * 32 + co];
            double bias = (double)sb1[co];
            double m = 0.0;
            #pragma unroll
            for (int dy = 0; dy < 2; ++dy)
            #pragma unroll
            for (int dx = 0; dx < 2; ++dx) {
                const float* sp = &simg[(2 * py + dy + 1) * 30 + (2 * px + dx + 1)];
                double a = bias;
                a = fma((double)sp[-31], wv[0], a);
                a = fma((double)sp[-30], wv[1], a);
                a = fma((double)sp[-29], wv[2], a);
                a = fma((double)sp[ -1], wv[3], a);
                a = fma((double)sp[  0], wv[4], a);
                a = fma((double)sp[  1], wv[5], a);
                a = fma((double)sp[ 29], wv[6], a);
                a = fma((double)sp[ 30], wv[7], a);
                a = fma((double)sp[ 31], wv[8], a);
                if (a < 0.0) a = 0.0;
                if (a > m) m = a;
            }
            h1q[((py + 1) * 16 + (px + 1)) * 5 + ch] = m;
        }
        // ---- stage cw2 octant as f64: per tap 128 consecutive floats (4ci x 32co) ----
        for (int w = t; w < 1152; w += 256) {
            int tap = w >> 7, k = w & 127;
            wq[w] = (double)cw2[tap * 1024 + oct * 128 + k];
        }
        __syncthreads();
        // ---- conv2 partial accumulate: pure ds_read + f64 FMA ----
        if (t < 196) {
            #pragma unroll
            for (int ky = 0; ky < 3; ++ky)
            #pragma unroll
            for (int kx = 0; kx < 3; ++kx) {
                const double* wb0 = &wq[(ky * 3 + kx) * 128 + co8];
                const double* hb = &h1q[cbase + (ky * 16 + kx) * 5];
                #pragma unroll
                for (int ci = 0; ci < 4; ++ci) {
                    const double* wp = wb0 + ci * 32;
                    double w0 = wp[0], w1 = wp[1], w2 = wp[2], w3 = wp[3];
                    double w4 = wp[4], w5 = wp[5], w6 = wp[6], w7 = wp[7];
                    #pragma unroll
                    for (int dy = 0; dy < 2; ++dy)
                    #pragma unroll
                    for (int dx = 0; dx < 2; ++dx) {
                        double av = hb[(dy * 16 + dx) * 5 + ci];
                        acc[dy][dx][0] = fma(av, w0, acc[dy][dx][0]);
                        acc[dy][dx][1] = fma(av, w1, acc[dy][dx][1]);
                        acc[dy][dx][2] = fma(av, w2, acc[dy][dx][2]);
                        acc[dy][dx][3] = fma(av, w3, acc[dy][dx][3]);
                        acc[dy][dx][4] = fma(av, w4, acc[dy][dx][4]);
                        acc[dy][dx][5] = fma(av, w5, acc[dy][dx][5]);
                        acc[dy][dx][6] = fma(av, w6, acc[dy][dx][6]);
                        acc[dy][dx][7] = fma(av, w7, acc[dy][dx][7]);
                    }
                }
            }
        }
    }
    __syncthreads();   // last conv2 reads of h1q/wq done; h2s overlay becomes legal
    // ---- conv2 relu + pool -> h2s ----
    if (t < 196) {
        #pragma unroll
        for (int q = 0; q < 8; ++q) {
            double m = 0.0;
            #pragma unroll
            for (int dy = 0; dy < 2; ++dy)
            #pragma unroll
            for (int dx = 0; dx < 2; ++dx) {
                double a = acc[dy][dx][q];
                if (a < 0.0) a = 0.0;
                if (a > m) m = a;
            }
            h2s[p2 * 33 + co8 + q] = m;
        }
    }
    // ---- conv3 + relu, ci-quartered, f64-staged weights (over dead phase-1 buffers) ----
    double a0 = 0.0, a1 = 0.0, a2 = 0.0, a3 = 0.0;
    int p3 = t >> 2, co4 = (t & 3) * 4;
    int py3 = p3 / 7, px3 = p3 % 7;
    if (t < 196) {
        a0 = (double)sb3[co4]; a1 = (double)sb3[co4 + 1];
        a2 = (double)sb3[co4 + 2]; a3 = (double)sb3[co4 + 3];
    }
    for (int qq = 0; qq < 4; ++qq) {
        __syncthreads();   // h2s written (first iter) / previous quarter's wq3 reads done
        for (int w = t; w < 1152; w += 256) {   // per tap: 8ci x 16co = 128 consecutive floats
            int tap = w >> 7, k = w & 127;
            wq3[w] = (double)cw3[tap * 512 + qq * 128 + k];
        }
        __syncthreads();
        if (t < 196) {
            for (int ky = 0; ky < 3; ++ky) {
                int iy = py3 + ky - 1; if ((unsigned)iy >= 7u) continue;
                for (int kx = 0; kx < 3; ++kx) {
                    int ix = px3 + kx - 1; if ((unsigned)ix >= 7u) continue;
                    const double* hp = &h2s[(iy * 7 + ix) * 33 + qq * 8];
                    const double* wp = &wq3[(ky * 3 + kx) * 128 + co4];
                    #pragma unroll
                    for (int ci = 0; ci < 8; ++ci) {
                        double av = hp[ci];
                        const double* wv = wp + ci * 16;
                        a0 = fma(av, wv[0], a0); a1 = fma(av, wv[1], a1);
                        a2 = fma(av, wv[2], a2); a3 = fma(av, wv[3], a3);
                    }
                }
            }
        }
    }
    __syncthreads();   // all conv3 reads of h2s done -> c3 may overwrite h2s head
    if (t < 196) {
        c3[p3 * 16 + co4 + 0] = a0 > 0.0 ? a0 : 0.0;
        c3[p3 * 16 + co4 + 1] = a1 > 0.0 ? a1 : 0.0;
        c3[p3 * 16 + co4 + 2] = a2 > 0.0 ? a2 : 0.0;
        c3[p3 * 16 + co4 + 3] = a3 > 0.0 ? a3 : 0.0;
    }
    __syncthreads();
    // ---- dense 784x16 ----
    {
        int part = t >> 4, o = t & 15, j0 = part * 49;
        double s = 0.0;
        for (int j = 0; j < 49; ++j) s = fma(c3[j0 + j], (double)dw[(size_t)(j0 + j) * 16 + o], s);
        red[part * 16 + o] = s;
    }
    __syncthreads();
    if (t < 16) {
        double e = (double)sdb[t];
        for (int q = 0; q < 16; ++q) e += red[q * 16 + t];
        Enc[(size_t)n * 16 + t] = e;
        se[t] = e;
    }
    __syncthreads();
    if (t == 0) {
        double s = 0.0;
        for (int q = 0; q < 16; ++q) s += se[q] * se[q];
        esqd[n] = s;
    }
}

// ---------------- fp32 gram -> d^2 filter keys; coalesced mirror via LDS transpose ----------------
__global__ __launch_bounds__(256) void k_gram(const float* __restrict__ x, const float* __restrict__ sqnf,
                                              float* __restrict__ Dm) {
    __shared__ float As[16][128];
    __shared__ float Bs[16][128];
    __shared__ float Cs[64 * 68];
    int id = blockIdx.x;
    int bi = (int)((sqrtf(8.f * (float)id + 1.f) - 1.f) * 0.5f);
    while ((bi + 1) * (bi + 2) / 2 <= id) ++bi;
    while (bi * (bi + 1) / 2 > id) --bi;
    int bj = id - bi * (bi + 1) / 2;
    int i0 = bi * 128, j0 = bj * 128;
    int t = threadIdx.x;
    int tx = t & 15, ty = t >> 4;
    int lrow = t >> 1, lk = (t & 1) * 8;
    float acc[8][8];
    #pragma unroll
    for (int r = 0; r < 8; ++r)
    #pragma unroll
    for (int c = 0; c < 8; ++c) acc[r][c] = 0.f;
    const float* arow = x + (size_t)(i0 + lrow) * DIM + lk;
    const float* brow = x + (size_t)(j0 + lrow) * DIM + lk;
    for (int kk = 0; kk < DIM; kk += 16) {
        float4 a0 = *(const float4*)(arow + kk);
        float4 a1 = *(const float4*)(arow + kk + 4);
        float4 b0 = *(const float4*)(brow + kk);
        float4 b1 = *(const float4*)(brow + kk + 4);
        __syncthreads();
        As[lk + 0][lrow] = a0.x; As[lk + 1][lrow] = a0.y; As[lk + 2][lrow] = a0.z; As[lk + 3][lrow] = a0.w;
        As[lk + 4][lrow] = a1.x; As[lk + 5][lrow] = a1.y; As[lk + 6][lrow] = a1.z; As[lk + 7][lrow] = a1.w;
        Bs[lk + 0][lrow] = b0.x; Bs[lk + 1][lrow] = b0.y; Bs[lk + 2][lrow] = b0.z; Bs[lk + 3][lrow] = b0.w;
        Bs[lk + 4][lrow] = b1.x; Bs[lk + 5][lrow] = b1.y; Bs[lk + 6][lrow] = b1.z; Bs[lk + 7][lrow] = b1.w;
        __syncthreads();
        #pragma unroll
        for (int k = 0; k < 16; ++k) {
            float4 av0 = *(const float4*)&As[k][ty * 8];
            float4 av1 = *(const float4*)&As[k][ty * 8 + 4];
            float4 bv0 = *(const float4*)&Bs[k][tx * 8];
            float4 bv1 = *(const float4*)&Bs[k][tx * 8 + 4];
            float a[8] = {av0.x, av0.y, av0.z, av0.w, av1.x, av1.y, av1.z, av1.w};
            float bb[8] = {bv0.x, bv0.y, bv0.z, bv0.w, bv1.x, bv1.y, bv1.z, bv1.w};
            #pragma unroll
            for (int r = 0; r < 8; ++r)
            #pragma unroll
            for (int c = 0; c < 8; ++c) acc[r][c] = fmaf(a[r], bb[c], acc[r][c]);
        }
    }
    float si[8], sj[8];
    #pragma unroll
    for (int r = 0; r < 8; ++r) si[r] = sqnf[i0 + ty * 8 + r];
    #pragma unroll
    for (int c = 0; c < 8; ++c) sj[c] = sqnf[j0 + tx * 8 + c];
    #pragma unroll
    for (int r = 0; r < 8; ++r)
    #pragma unroll
    for (int c = 0; c < 8; ++c) acc[r][c] = fmaxf(si[r] + sj[c] - 2.f * acc[r][c], 1e-12f);
    #pragma unroll
    for (int r = 0; r < 8; ++r) {
        size_t gi = (size_t)(i0 + ty * 8 + r) * NN + j0 + tx * 8;
        *(float4*)(Dm + gi)     = make_float4(acc[r][0], acc[r][1], acc[r][2], acc[r][3]);
        *(float4*)(Dm + gi + 4) = make_float4(acc[r][4], acc[r][5], acc[r][6], acc[r][7]);
    }
    if (bi != bj) {
        for (int qr = 0; qr < 2; ++qr)
        for (int qc = 0; qc < 2; ++qc) {
            __syncthreads();
            if ((ty >> 3) == qr && (tx >> 3) == qc) {
                int tx8 = tx & 7, ty8 = ty & 7;
                #pragma unroll
                for (int c = 0; c < 8; ++c) {
                    float* dst = &Cs[(tx8 * 8 + c) * 68 + ty8 * 8];
                    *(float4*)dst       = make_float4(acc[0][c], acc[1][c], acc[2][c], acc[3][c]);
                    *(float4*)(dst + 4) = make_float4(acc[4][c], acc[5][c], acc[6][c], acc[7][c]);
                }
            }
            __syncthreads();
            #pragma unroll
            for (int g = 0; g < 4; ++g) {
                int idx = t + g * 256;
                int a = idx >> 4, f4i = idx & 15;
                float4 v = *(float4*)&Cs[a * 68 + f4i * 4];
                *(float4*)&Dm[(size_t)(j0 + qc * 64 + a) * NN + i0 + qr * 64 + f4i * 4] = v;
            }
        }
    }
}

// ---------------- selection: register keys + 3-pass radix threshold -> ~66 cands, f64 refine + exact rank ----------------
__global__ __launch_bounds__(256) void k_topsel(const float* __restrict__ Dm, const double* __restrict__ sqnd,
                                                const float* __restrict__ x,
                                                double* __restrict__ topvd, int* __restrict__ topi) {
    __shared__ float xi[DIM];
    __shared__ unsigned hist[256];
    __shared__ unsigned sfx[256];
    __shared__ unsigned sh_pref, sh_need;
    __shared__ int cj[CAP];
    __shared__ double cvd[CAP];
    __shared__ unsigned ncnt;
    int i = blockIdx.x, t = threadIdx.x;
    const float* drow = Dm + (size_t)i * NN;
    unsigned uk[16];
    #pragma unroll
    for (int s = 0; s < 16; ++s) {
        int j = t + s * 256;
        unsigned u = __float_as_uint(drow[j]);
        uk[s] = (j == i) ? 0u : u;
    }
    for (int d = t; d < DIM; d += 256) xi[d] = x[(size_t)i * DIM + d];
    if (t == 0) ncnt = 0;
    unsigned prefix = 0, need = 63;
    for (int pass = 0; pass < 3; ++pass) {
        int shift = 24 - pass * 8;
        hist[t] = 0;
        __syncthreads();
        #pragma unroll
        for (int s = 0; s < 16; ++s) {
            unsigned u = uk[s];
            bool ok = (pass == 0) || ((u >> (shift + 8)) == prefix);
            if (ok) atomicAdd(&hist[(u >> shift) & 255u], 1u);
        }
        __syncthreads();
        sfx[t] = hist[t];
        __syncthreads();
        for (int off = 1; off < 256; off <<= 1) {
            unsigned add = (t + off < 256) ? sfx[t + off] : 0u;
            __syncthreads();
            sfx[t] += add;
            __syncthreads();
        }
        if (sfx[t] >= need && (t == 255 || sfx[t + 1] < need)) {
            sh_pref = (prefix << 8) | (unsigned)t;
            sh_need = need - ((t == 255) ? 0u : sfx[t + 1]);
        }
        __syncthreads();
        prefix = sh_pref; need = sh_need;
        __syncthreads();
    }
    #pragma unroll
    for (int s = 0; s < 16; ++s) {
        if ((uk[s] >> 8) >= prefix) {
            unsigned p = atomicAdd(&ncnt, 1u);
            if (p < CAP) cj[p] = t + s * 256;
        }
    }
    __syncthreads();
    int ncand = min((int)ncnt, CAP);
    double sqi_d = sqnd[i];
    int lane = t & 63, w = t >> 6;
    const float4* xi4 = (const float4*)xi;
    for (int c = w; c < ncand; c += 4) {
        const float4* xj4 = (const float4*)(x + (size_t)cj[c] * DIM);
        double s = 0.0;
        for (int k = lane; k < 196; k += 64) {
            float4 a = xi4[k]; float4 b = xj4[k];
            s = fma((double)a.x, (double)b.x, s);
            s = fma((double)a.y, (double)b.y, s);
            s = fma((double)a.z, (double)b.z, s);
            s = fma((double)a.w, (double)b.w, s);
        }
        for (int o = 32; o > 0; o >>= 1) s += __shfl_down(s, o);
        if (lane == 0) cvd[c] = sqrt(fmax(sqi_d + sqnd[cj[c]] - 2.0 * s, 1e-12));
    }
    __syncthreads();
    if (t < ncand) {
        double v = cvd[t]; int jj = cj[t];
        int r = 0;
        for (int c2 = 0; c2 < ncand; ++c2) {
            double v2 = cvd[c2];
            if (v2 > v || (v2 == v && cj[c2] < jj)) ++r;
        }
        if (r >= 1 && r < 63) {
            topvd[(size_t)i * K62 + r - 1] = v;
            topi[(size_t)i * K62 + r - 1] = jj;
        }
    }
}

// ---------------- encoded distances (np cancellation form, f64) + ratio sum ----------------
__global__ __launch_bounds__(256) void k_ratio(const double* __restrict__ Enc, const double* __restrict__ esqd,
                                               const double* __restrict__ topvd, const int* __restrict__ topi,
                                               double* __restrict__ vencd, double* __restrict__ Ssum) {
    int r = blockIdx.x * 4 + (threadIdx.x >> 6);
    int lane = threadIdx.x & 63;
    double ratio = 0.0;
    if (lane < K62) {
        int j = topi[(size_t)r * K62 + lane];
        const double* Er = Enc + (size_t)r * 16;
        const double* Ej = Enc + (size_t)j * 16;
        double dot = 0.0;
        #pragma unroll
        for (int q = 0; q < 16; ++q) dot = fma(Er[q], Ej[q], dot);
        double ve = sqrt(fmax(esqd[r] + esqd[j] - 2.0 * dot, 1e-12));
        vencd[(size_t)r * K62 + lane] = ve;
        ratio = topvd[(size_t)r * K62 + lane] / ve;
    }
    for (int o = 32; o > 0; o >>= 1) ratio += __shfl_down(ratio, o);
    if (lane == 0) atomicAdd(Ssum, ratio);
}

// ---------------- final loss ----------------
__global__ __launch_bounds__(256) void k_loss(const double* __restrict__ topvd, const double* __restrict__ vencd,
                                              const double* __restrict__ Ssum, double* __restrict__ Lsum) {
    int r = blockIdx.x * 4 + (threadIdx.x >> 6);
    int lane = threadIdx.x & 63;
    double m = Ssum[0] * (1.0 / (4096.0 * 62.0));
    double v = -1.0;
    if (lane < K62) {
        double d = topvd[(size_t)r * K62 + lane] - m * vencd[(size_t)r * K62 + lane];
        v = d * d;
    }
    for (int o = 32; o > 0; o >>= 1) { double ov = __shfl_down(v, o); v = (ov > v) ? ov : v; }
    if (lane == 0) atomicAdd(Lsum, v);
}

__global__ __launch_bounds__(64) void k_final(const double* __restrict__ Lsum, float* __restrict__ out) {
    if (threadIdx.x == 0) out[0] = (float)(Lsum[0] * (1.0 / 4096.0));
}

extern "C" void kernel_launch(void* const* d_in, const int* in_sizes, int n_in,
                              void* d_out, int out_size, void* d_ws, size_t ws_size,
                              hipStream_t stream) {
    const float* x   = (const float*)d_in[0];
    const float* cw1 = (const float*)d_in[1];
    const float* cb1 = (const float*)d_in[2];
    const float* cw2 = (const float*)d_in[3];
    const float* cb2 = (const float*)d_in[4];
    const float* cw3 = (const float*)d_in[5];
    const float* cb3 = (const float*)d_in[6];
    const float* dw  = (const float*)d_in[7];
    const float* db  = (const float*)d_in[8];

    float*  ws    = (float*)d_ws;
    float*  Dm    = ws;                          // 16,777,216 f = 64 MB
    double* Enc   = (double*)(ws + 16777216);    // 65,536 d
    double* esqd  = Enc + 65536;                 // 4,096 d
    double* sqnd  = esqd + 4096;                 // 4,096 d
    float*  sqnf  = (float*)(sqnd + 4096);       // 4,096 f
    double* topvd = (double*)(sqnf + 4096);      // 253,952 d
    double* vencd = topvd + 253952;              // 253,952 d
    double* Ssum  = vencd + 253952;              // 1 d
    double* Lsum  = Ssum + 1;                    // 1 d
    int*    topi  = (int*)(Lsum + 1);            // 253,952 i
    float*  out   = (float*)d_out;

    k_init<<<1, 64, 0, stream>>>(Ssum, Lsum);
    k_sqnorm<<<1024, 256, 0, stream>>>(x, sqnd, sqnf);
    k_encoder<<<4096, 256, 0, stream>>>(x, cw1, cb1, cw2, cb2, cw3, cb3, dw, db, Enc, esqd);
    k_gram<<<528, 256, 0, stream>>>(x, sqnf, Dm);
    k_topsel<<<4096, 256, 0, stream>>>(Dm, sqnd, x, topvd, topi);
    k_ratio<<<1024, 256, 0, stream>>>(Enc, esqd, topvd, topi, vencd, Ssum);
    k_loss<<<1024, 256, 0, stream>>>(topvd, vencd, Ssum, Lsum);
    k_final<<<1, 64, 0, stream>>>(Lsum, out);
}

// Round 12
// 990.914 us; speedup vs baseline: 6.7602x; 6.7602x over previous
//
#include <hip/hip_runtime.h>
#include <math.h>

#define NN 4096
#define DIM 784
#define K62 62
#define CAP 128

// ---------------- init ----------------
__global__ __launch_bounds__(64) void k_init(double* Ssum, double* Lsum) {
    if (threadIdx.x == 0) { Ssum[0] = 0.0; Lsum[0] = 0.0; }
}

// ---------------- squared row norms: f64 exact + f32 for keys ----------------
__global__ __launch_bounds__(256) void k_sqnorm(const float* __restrict__ x, double* __restrict__ sqnd,
                                                float* __restrict__ sqnf) {
    int r = blockIdx.x * 4 + (threadIdx.x >> 6);
    int lane = threadIdx.x & 63;
    const float* xr = x + (size_t)r * DIM;
    double s = 0.0;
    for (int k = lane; k < DIM; k += 64) { double v = (double)xr[k]; s += v * v; }
    for (int o = 32; o > 0; o >>= 1) s += __shfl_down(s, o);
    if (lane == 0) { sqnd[r] = s; sqnf[r] = (float)s; }
}

// ---------------- fused all-f64 encoder: 25744 B LDS -> 6 blocks/CU (LDS-bound), VGPR-safe bounds ----------------
// NOTE: __launch_bounds__ second arg = min waves per SIMD. (256,6) in R11 capped VGPR at 40 and
// spilled the 64-VGPR conv2 accumulator to scratch (26 GB traffic, 7x slowdown). (256,4) gives the
// allocator 128 VGPRs; it uses 64; occupancy is then LDS-limited at 6 blocks/CU as intended.
__global__ __launch_bounds__(256, 4) void k_encoder(const float* __restrict__ x,
    const float* __restrict__ cw1, const float* __restrict__ cb1,
    const float* __restrict__ cw2, const float* __restrict__ cb2,
    const float* __restrict__ cw3, const float* __restrict__ cb3,
    const float* __restrict__ dw, const float* __restrict__ db,
    double* __restrict__ Enc, double* __restrict__ esqd)
{
    __shared__ __align__(16) unsigned char SB[25744];
    float*  sb1  = (float*)(SB);             // 32 f  [0,128)
    float*  sb2  = (float*)(SB + 128);       // 32 f  [128,256)
    float*  sb3  = (float*)(SB + 256);       // 16 f  [256,320)
    float*  sdb  = (float*)(SB + 320);       // 16 f  [320,384)
    float*  simg = (float*)(SB + 384);       // 900 f = 3600  [384,3984)
    double* scw1 = (double*)(SB + 3984);     // 288 d = 2304  [3984,6288)
    double* h1q  = (double*)(SB + 6288);     // 1280 d = 10240 [6288,16528)
    double* wq   = (double*)(SB + 16528);    // 1152 d = 9216  [16528,25744)
    // overlays (phase 2/3; legality guarded by the existing syncs):
    double* wq3  = (double*)(SB + 384);      // 1152 d over simg+scw1+h1q-head (all dead in phase 2)
    double* h2s  = (double*)(SB + 9600);     // 1617 d over h1q-tail+wq (dead in phase 2)
    double* c3   = (double*)(SB + 9600);     // 784 d over h2s head (after conv3 reads)
    double* red  = (double*)(SB + 15872);    // 256 d
    double* se   = (double*)(SB + 17920);    // 16 d

    int n = blockIdx.x, t = threadIdx.x;
    // zero padded buffers
    for (int idx = t; idx < 1280; idx += 256) h1q[idx] = 0.0;
    for (int idx = t; idx < 900; idx += 256) simg[idx] = 0.f;
    __syncthreads();
    // load image interior (28 rows of 7 float4); cw1 cvt once to f64; biases f32
    if (t < 196) {
        int row = t / 7, c4 = t % 7;
        float4 v = ((const float4*)(x + (size_t)n * DIM))[t];
        float* d = &simg[(row + 1) * 30 + 1 + c4 * 4];
        d[0] = v.x; d[1] = v.y; d[2] = v.z; d[3] = v.w;
    }
    for (int idx = t; idx < 288; idx += 256) scw1[idx] = (double)cw1[idx];
    if (t < 32) { sb1[t] = cb1[t]; sb2[t] = cb2[t]; }
    if (t < 16) { sb3[t] = cb3[t]; sdb[t] = db[t]; }
    __syncthreads();

    int p2 = t >> 2, co8 = (t & 3) * 8;
    int py2 = p2 / 7, px2 = p2 % 7;
    int cbase = ((2 * py2) * 16 + 2 * px2) * 5;   // padded h1q base (doubles)
    double acc[2][2][8];
    if (t < 196) {
        #pragma unroll
        for (int dy = 0; dy < 2; ++dy)
        #pragma unroll
        for (int dx = 0; dx < 2; ++dx)
        #pragma unroll
        for (int q = 0; q < 8; ++q) acc[dy][dx][q] = (double)sb2[co8 + q];
    }

    for (int oct = 0; oct < 8; ++oct) {
        __syncthreads();   // protect h1q/wq from previous octant's readers
        // ---- conv1 + relu + pool for channels [4*oct, 4*oct+4): f64 weights, f32 image (exact cvt) ----
        for (int o = t; o < 784; o += 256) {
            int ch = o & 3, p = o >> 2;
            int py = p / 14, px = p % 14;
            int co = (oct << 2) + ch;
            double wv[9];
            #pragma unroll
            for (int tp = 0; tp < 9; ++tp) wv[tp] = scw1[tp * 32 + co];
            double bias = (double)sb1[co];
            double m = 0.0;
            #pragma unroll
            for (int dy = 0; dy < 2; ++dy)
            #pragma unroll
            for (int dx = 0; dx < 2; ++dx) {
                const float* sp = &simg[(2 * py + dy + 1) * 30 + (2 * px + dx + 1)];
                double a = bias;
                a = fma((double)sp[-31], wv[0], a);
                a = fma((double)sp[-30], wv[1], a);
                a = fma((double)sp[-29], wv[2], a);
                a = fma((double)sp[ -1], wv[3], a);
                a = fma((double)sp[  0], wv[4], a);
                a = fma((double)sp[  1], wv[5], a);
                a = fma((double)sp[ 29], wv[6], a);
                a = fma((double)sp[ 30], wv[7], a);
                a = fma((double)sp[ 31], wv[8], a);
                if (a < 0.0) a = 0.0;
                if (a > m) m = a;
            }
            h1q[((py + 1) * 16 + (px + 1)) * 5 + ch] = m;
        }
        // ---- stage cw2 octant as f64: per tap 128 consecutive floats (4ci x 32co) ----
        for (int w = t; w < 1152; w += 256) {
            int tap = w >> 7, k = w & 127;
            wq[w] = (double)cw2[tap * 1024 + oct * 128 + k];
        }
        __syncthreads();
        // ---- conv2 partial accumulate: pure ds_read + f64 FMA ----
        if (t < 196) {
            #pragma unroll
            for (int ky = 0; ky < 3; ++ky)
            #pragma unroll
            for (int kx = 0; kx < 3; ++kx) {
                const double* wb0 = &wq[(ky * 3 + kx) * 128 + co8];
                const double* hb = &h1q[cbase + (ky * 16 + kx) * 5];
                #pragma unroll
                for (int ci = 0; ci < 4; ++ci) {
                    const double* wp = wb0 + ci * 32;
                    double w0 = wp[0], w1 = wp[1], w2 = wp[2], w3 = wp[3];
                    double w4 = wp[4], w5 = wp[5], w6 = wp[6], w7 = wp[7];
                    #pragma unroll
                    for (int dy = 0; dy < 2; ++dy)
                    #pragma unroll
                    for (int dx = 0; dx < 2; ++dx) {
                        double av = hb[(dy * 16 + dx) * 5 + ci];
                        acc[dy][dx][0] = fma(av, w0, acc[dy][dx][0]);
                        acc[dy][dx][1] = fma(av, w1, acc[dy][dx][1]);
                        acc[dy][dx][2] = fma(av, w2, acc[dy][dx][2]);
                        acc[dy][dx][3] = fma(av, w3, acc[dy][dx][3]);
                        acc[dy][dx][4] = fma(av, w4, acc[dy][dx][4]);
                        acc[dy][dx][5] = fma(av, w5, acc[dy][dx][5]);
                        acc[dy][dx][6] = fma(av, w6, acc[dy][dx][6]);
                        acc[dy][dx][7] = fma(av, w7, acc[dy][dx][7]);
                    }
                }
            }
        }
    }
    __syncthreads();   // last conv2 reads of h1q/wq done; h2s overlay becomes legal
    // ---- conv2 relu + pool -> h2s ----
    if (t < 196) {
        #pragma unroll
        for (int q = 0; q < 8; ++q) {
            double m = 0.0;
            #pragma unroll
            for (int dy = 0; dy < 2; ++dy)
            #pragma unroll
            for (int dx = 0; dx < 2; ++dx) {
                double a = acc[dy][dx][q];
                if (a < 0.0) a = 0.0;
                if (a > m) m = a;
            }
            h2s[p2 * 33 + co8 + q] = m;
        }
    }
    // ---- conv3 + relu, ci-quartered, f64-staged weights (over dead phase-1 buffers) ----
    double a0 = 0.0, a1 = 0.0, a2 = 0.0, a3 = 0.0;
    int p3 = t >> 2, co4 = (t & 3) * 4;
    int py3 = p3 / 7, px3 = p3 % 7;
    if (t < 196) {
        a0 = (double)sb3[co4]; a1 = (double)sb3[co4 + 1];
        a2 = (double)sb3[co4 + 2]; a3 = (double)sb3[co4 + 3];
    }
    for (int qq = 0; qq < 4; ++qq) {
        __syncthreads();   // h2s written (first iter) / previous quarter's wq3 reads done
        for (int w = t; w < 1152; w += 256) {   // per tap: 8ci x 16co = 128 consecutive floats
            int tap = w >> 7, k = w & 127;
            wq3[w] = (double)cw3[tap * 512 + qq * 128 + k];
        }
        __syncthreads();
        if (t < 196) {
            for (int ky = 0; ky < 3; ++ky) {
                int iy = py3 + ky - 1; if ((unsigned)iy >= 7u) continue;
                for (int kx = 0; kx < 3; ++kx) {
                    int ix = px3 + kx - 1; if ((unsigned)ix >= 7u) continue;
                    const double* hp = &h2s[(iy * 7 + ix) * 33 + qq * 8];
                    const double* wp = &wq3[(ky * 3 + kx) * 128 + co4];
                    #pragma unroll
                    for (int ci = 0; ci < 8; ++ci) {
                        double av = hp[ci];
                        const double* wv = wp + ci * 16;
                        a0 = fma(av, wv[0], a0); a1 = fma(av, wv[1], a1);
                        a2 = fma(av, wv[2], a2); a3 = fma(av, wv[3], a3);
                    }
                }
            }
        }
    }
    __syncthreads();   // all conv3 reads of h2s done -> c3 may overwrite h2s head
    if (t < 196) {
        c3[p3 * 16 + co4 + 0] = a0 > 0.0 ? a0 : 0.0;
        c3[p3 * 16 + co4 + 1] = a1 > 0.0 ? a1 : 0.0;
        c3[p3 * 16 + co4 + 2] = a2 > 0.0 ? a2 : 0.0;
        c3[p3 * 16 + co4 + 3] = a3 > 0.0 ? a3 : 0.0;
    }
    __syncthreads();
    // ---- dense 784x16 ----
    {
        int part = t >> 4, o = t & 15, j0 = part * 49;
        double s = 0.0;
        for (int j = 0; j < 49; ++j) s = fma(c3[j0 + j], (double)dw[(size_t)(j0 + j) * 16 + o], s);
        red[part * 16 + o] = s;
    }
    __syncthreads();
    if (t < 16) {
        double e = (double)sdb[t];
        for (int q = 0; q < 16; ++q) e += red[q * 16 + t];
        Enc[(size_t)n * 16 + t] = e;
        se[t] = e;
    }
    __syncthreads();
    if (t == 0) {
        double s = 0.0;
        for (int q = 0; q < 16; ++q) s += se[q] * se[q];
        esqd[n] = s;
    }
}

// ---------------- fp32 gram -> d^2 filter keys; coalesced mirror via LDS transpose ----------------
__global__ __launch_bounds__(256) void k_gram(const float* __restrict__ x, const float* __restrict__ sqnf,
                                              float* __restrict__ Dm) {
    __shared__ float As[16][128];
    __shared__ float Bs[16][128];
    __shared__ float Cs[64 * 68];
    int id = blockIdx.x;
    int bi = (int)((sqrtf(8.f * (float)id + 1.f) - 1.f) * 0.5f);
    while ((bi + 1) * (bi + 2) / 2 <= id) ++bi;
    while (bi * (bi + 1) / 2 > id) --bi;
    int bj = id - bi * (bi + 1) / 2;
    int i0 = bi * 128, j0 = bj * 128;
    int t = threadIdx.x;
    int tx = t & 15, ty = t >> 4;
    int lrow = t >> 1, lk = (t & 1) * 8;
    float acc[8][8];
    #pragma unroll
    for (int r = 0; r < 8; ++r)
    #pragma unroll
    for (int c = 0; c < 8; ++c) acc[r][c] = 0.f;
    const float* arow = x + (size_t)(i0 + lrow) * DIM + lk;
    const float* brow = x + (size_t)(j0 + lrow) * DIM + lk;
    for (int kk = 0; kk < DIM; kk += 16) {
        float4 a0 = *(const float4*)(arow + kk);
        float4 a1 = *(const float4*)(arow + kk + 4);
        float4 b0 = *(const float4*)(brow + kk);
        float4 b1 = *(const float4*)(brow + kk + 4);
        __syncthreads();
        As[lk + 0][lrow] = a0.x; As[lk + 1][lrow] = a0.y; As[lk + 2][lrow] = a0.z; As[lk + 3][lrow] = a0.w;
        As[lk + 4][lrow] = a1.x; As[lk + 5][lrow] = a1.y; As[lk + 6][lrow] = a1.z; As[lk + 7][lrow] = a1.w;
        Bs[lk + 0][lrow] = b0.x; Bs[lk + 1][lrow] = b0.y; Bs[lk + 2][lrow] = b0.z; Bs[lk + 3][lrow] = b0.w;
        Bs[lk + 4][lrow] = b1.x; Bs[lk + 5][lrow] = b1.y; Bs[lk + 6][lrow] = b1.z; Bs[lk + 7][lrow] = b1.w;
        __syncthreads();
        #pragma unroll
        for (int k = 0; k < 16; ++k) {
            float4 av0 = *(const float4*)&As[k][ty * 8];
            float4 av1 = *(const float4*)&As[k][ty * 8 + 4];
            float4 bv0 = *(const float4*)&Bs[k][tx * 8];
            float4 bv1 = *(const float4*)&Bs[k][tx * 8 + 4];
            float a[8] = {av0.x, av0.y, av0.z, av0.w, av1.x, av1.y, av1.z, av1.w};
            float bb[8] = {bv0.x, bv0.y, bv0.z, bv0.w, bv1.x, bv1.y, bv1.z, bv1.w};
            #pragma unroll
            for (int r = 0; r < 8; ++r)
            #pragma unroll
            for (int c = 0; c < 8; ++c) acc[r][c] = fmaf(a[r], bb[c], acc[r][c]);
        }
    }
    float si[8], sj[8];
    #pragma unroll
    for (int r = 0; r < 8; ++r) si[r] = sqnf[i0 + ty * 8 + r];
    #pragma unroll
    for (int c = 0; c < 8; ++c) sj[c] = sqnf[j0 + tx * 8 + c];
    #pragma unroll
    for (int r = 0; r < 8; ++r)
    #pragma unroll
    for (int c = 0; c < 8; ++c) acc[r][c] = fmaxf(si[r] + sj[c] - 2.f * acc[r][c], 1e-12f);
    #pragma unroll
    for (int r = 0; r < 8; ++r) {
        size_t gi = (size_t)(i0 + ty * 8 + r) * NN + j0 + tx * 8;
        *(float4*)(Dm + gi)     = make_float4(acc[r][0], acc[r][1], acc[r][2], acc[r][3]);
        *(float4*)(Dm + gi + 4) = make_float4(acc[r][4], acc[r][5], acc[r][6], acc[r][7]);
    }
    if (bi != bj) {
        for (int qr = 0; qr < 2; ++qr)
        for (int qc = 0; qc < 2; ++qc) {
            __syncthreads();
            if ((ty >> 3) == qr && (tx >> 3) == qc) {
                int tx8 = tx & 7, ty8 = ty & 7;
                #pragma unroll
                for (int c = 0; c < 8; ++c) {
                    float* dst = &Cs[(tx8 * 8 + c) * 68 + ty8 * 8];
                    *(float4*)dst       = make_float4(acc[0][c], acc[1][c], acc[2][c], acc[3][c]);
                    *(float4*)(dst + 4) = make_float4(acc[4][c], acc[5][c], acc[6][c], acc[7][c]);
                }
            }
            __syncthreads();
            #pragma unroll
            for (int g = 0; g < 4; ++g) {
                int idx = t + g * 256;
                int a = idx >> 4, f4i = idx & 15;
                float4 v = *(float4*)&Cs[a * 68 + f4i * 4];
                *(float4*)&Dm[(size_t)(j0 + qc * 64 + a) * NN + i0 + qr * 64 + f4i * 4] = v;
            }
        }
    }
}

// ---------------- selection: register keys + 3-pass radix threshold -> ~66 cands, f64 refine + exact rank ----------------
__global__ __launch_bounds__(256) void k_topsel(const float* __restrict__ Dm, const double* __restrict__ sqnd,
                                                const float* __restrict__ x,
                                                double* __restrict__ topvd, int* __restrict__ topi) {
    __shared__ float xi[DIM];
    __shared__ unsigned hist[256];
    __shared__ unsigned sfx[256];
    __shared__ unsigned sh_pref, sh_need;
    __shared__ int cj[CAP];
    __shared__ double cvd[CAP];
    __shared__ unsigned ncnt;
    int i = blockIdx.x, t = threadIdx.x;
    const float* drow = Dm + (size_t)i * NN;
    unsigned uk[16];
    #pragma unroll
    for (int s = 0; s < 16; ++s) {
        int j = t + s * 256;
        unsigned u = __float_as_uint(drow[j]);
        uk[s] = (j == i) ? 0u : u;
    }
    for (int d = t; d < DIM; d += 256) xi[d] = x[(size_t)i * DIM + d];
    if (t == 0) ncnt = 0;
    unsigned prefix = 0, need = 63;
    for (int pass = 0; pass < 3; ++pass) {
        int shift = 24 - pass * 8;
        hist[t] = 0;
        __syncthreads();
        #pragma unroll
        for (int s = 0; s < 16; ++s) {
            unsigned u = uk[s];
            bool ok = (pass == 0) || ((u >> (shift + 8)) == prefix);
            if (ok) atomicAdd(&hist[(u >> shift) & 255u], 1u);
        }
        __syncthreads();
        sfx[t] = hist[t];
        __syncthreads();
        for (int off = 1; off < 256; off <<= 1) {
            unsigned add = (t + off < 256) ? sfx[t + off] : 0u;
            __syncthreads();
            sfx[t] += add;
            __syncthreads();
        }
        if (sfx[t] >= need && (t == 255 || sfx[t + 1] < need)) {
            sh_pref = (prefix << 8) | (unsigned)t;
            sh_need = need - ((t == 255) ? 0u : sfx[t + 1]);
        }
        __syncthreads();
        prefix = sh_pref; need = sh_need;
        __syncthreads();
    }
    #pragma unroll
    for (int s = 0; s < 16; ++s) {
        if ((uk[s] >> 8) >= prefix) {
            unsigned p = atomicAdd(&ncnt, 1u);
            if (p < CAP) cj[p] = t + s * 256;
        }
    }
    __syncthreads();
    int ncand = min((int)ncnt, CAP);
    double sqi_d = sqnd[i];
    int lane = t & 63, w = t >> 6;
    const float4* xi4 = (const float4*)xi;
    for (int c = w; c < ncand; c += 4) {
        const float4* xj4 = (const float4*)(x + (size_t)cj[c] * DIM);
        double s = 0.0;
        for (int k = lane; k < 196; k += 64) {
            float4 a = xi4[k]; float4 b = xj4[k];
            s = fma((double)a.x, (double)b.x, s);
            s = fma((double)a.y, (double)b.y, s);
            s = fma((double)a.z, (double)b.z, s);
            s = fma((double)a.w, (double)b.w, s);
        }
        for (int o = 32; o > 0; o >>= 1) s += __shfl_down(s, o);
        if (lane == 0) cvd[c] = sqrt(fmax(sqi_d + sqnd[cj[c]] - 2.0 * s, 1e-12));
    }
    __syncthreads();
    if (t < ncand) {
        double v = cvd[t]; int jj = cj[t];
        int r = 0;
        for (int c2 = 0; c2 < ncand; ++c2) {
            double v2 = cvd[c2];
            if (v2 > v || (v2 == v && cj[c2] < jj)) ++r;
        }
        if (r >= 1 && r < 63) {
            topvd[(size_t)i * K62 + r - 1] = v;
            topi[(size_t)i * K62 + r - 1] = jj;
        }
    }
}

// ---------------- encoded distances (np cancellation form, f64) + ratio sum ----------------
__global__ __launch_bounds__(256) void k_ratio(const double* __restrict__ Enc, const double* __restrict__ esqd,
                                               const double* __restrict__ topvd, const int* __restrict__ topi,
                                               double* __restrict__ vencd, double* __restrict__ Ssum) {
    int r = blockIdx.x * 4 + (threadIdx.x >> 6);
    int lane = threadIdx.x & 63;
    double ratio = 0.0;
    if (lane < K62) {
        int j = topi[(size_t)r * K62 + lane];
        const double* Er = Enc + (size_t)r * 16;
        const double* Ej = Enc + (size_t)j * 16;
        double dot = 0.0;
        #pragma unroll
        for (int q = 0; q < 16; ++q) dot = fma(Er[q], Ej[q], dot);
        double ve = sqrt(fmax(esqd[r] + esqd[j] - 2.0 * dot, 1e-12));
        vencd[(size_t)r * K62 + lane] = ve;
        ratio = topvd[(size_t)r * K62 + lane] / ve;
    }
    for (int o = 32; o > 0; o >>= 1) ratio += __shfl_down(ratio, o);
    if (lane == 0) atomicAdd(Ssum, ratio);
}

// ---------------- final loss ----------------
__global__ __launch_bounds__(256) void k_loss(const double* __restrict__ topvd, const double* __restrict__ vencd,
                                              const double* __restrict__ Ssum, double* __restrict__ Lsum) {
    int r = blockIdx.x * 4 + (threadIdx.x >> 6);
    int lane = threadIdx.x & 63;
    double m = Ssum[0] * (1.0 / (4096.0 * 62.0));
    double v = -1.0;
    if (lane < K62) {
        double d = topvd[(size_t)r * K62 + lane] - m * vencd[(size_t)r * K62 + lane];
        v = d * d;
    }
    for (int o = 32; o > 0; o >>= 1) { double ov = __shfl_down(v, o); v = (ov > v) ? ov : v; }
    if (lane == 0) atomicAdd(Lsum, v);
}

__global__ __launch_bounds__(64) void k_final(const double* __restrict__ Lsum, float* __restrict__ out) {
    if (threadIdx.x == 0) out[0] = (float)(Lsum[0] * (1.0 / 4096.0));
}

extern "C" void kernel_launch(void* const* d_in, const int* in_sizes, int n_in,
                              void* d_out, int out_size, void* d_ws, size_t ws_size,
                              hipStream_t stream) {
    const float* x   = (const float*)d_in[0];
    const float* cw1 = (const float*)d_in[1];
    const float* cb1 = (const float*)d_in[2];
    const float* cw2 = (const float*)d_in[3];
    const float* cb2 = (const float*)d_in[4];
    const float* cw3 = (const float*)d_in[5];
    const float* cb3 = (const float*)d_in[6];
    const float* dw  = (const float*)d_in[7];
    const float* db  = (const float*)d_in[8];

    float*  ws    = (float*)d_ws;
    float*  Dm    = ws;                          // 16,777,216 f = 64 MB
    double* Enc   = (double*)(ws + 16777216);    // 65,536 d
    double* esqd  = Enc + 65536;                 // 4,096 d
    double* sqnd  = esqd + 4096;                 // 4,096 d
    float*  sqnf  = (float*)(sqnd + 4096);       // 4,096 f
    double* topvd = (double*)(sqnf + 4096);      // 253,952 d
    double* vencd = topvd + 253952;              // 253,952 d
    double* Ssum  = vencd + 253952;              // 1 d
    double* Lsum  = Ssum + 1;                    // 1 d
    int*    topi  = (int*)(Lsum + 1);            // 253,952 i
    float*  out   = (float*)d_out;

    k_init<<<1, 64, 0, stream>>>(Ssum, Lsum);
    k_sqnorm<<<1024, 256, 0, stream>>>(x, sqnd, sqnf);
    k_encoder<<<4096, 256, 0, stream>>>(x, cw1, cb1, cw2, cb2, cw3, cb3, dw, db, Enc, esqd);
    k_gram<<<528, 256, 0, stream>>>(x, sqnf, Dm);
    k_topsel<<<4096, 256, 0, stream>>>(Dm, sqnd, x, topvd, topi);
    k_ratio<<<1024, 256, 0, stream>>>(Enc, esqd, topvd, topi, vencd, Ssum);
    k_loss<<<1024, 256, 0, stream>>>(topvd, vencd, Ssum, Lsum);
    k_final<<<1, 64, 0, stream>>>(Lsum, out);
}